// Round 1
// baseline (157.050 us; speedup 1.0000x reference)
//
#include <hip/hip_runtime.h>
#include <hip/hip_bf16.h>
#include <stdint.h>

#define N_SAMP 8192
#define D_TOW  128
#define D_HID  128

typedef __bf16 bf16x8 __attribute__((ext_vector_type(8)));
typedef float  f32x4  __attribute__((ext_vector_type(4)));

__device__ __forceinline__ ushort f2bf(float f) {
  union { float f; uint32_t u; } c; c.f = f;
  uint32_t u = c.u;
  return (ushort)((u + 0x7FFFu + ((u >> 16) & 1u)) >> 16);  // RNE
}

// sigmoid via raw HW ops: v_exp_f32 + v_rcp_f32.
__device__ __forceinline__ float fast_sigmoid(float p) {
  float e = __builtin_amdgcn_exp2f(p * -1.442695040888963f);
  return __builtin_amdgcn_rcpf(1.0f + e);
}

// fp32 -> bf16 convert. W0 is pre-scaled by -log2(e) so the towers MFMA
// directly produces exp2 arguments (saves one VALU mul per sigmoid).
// x path emits a per-block "saw non-binary" flag UNCONDITIONALLY, which
// removes the hipMemsetAsync node (no init needed).
__global__ __launch_bounds__(256) void prep_kernel(
    const float* __restrict__ x, const float* __restrict__ w0,
    ushort* __restrict__ xb, ushort* __restrict__ w0b,
    int* __restrict__ flagArr) {
  const int NX4 = (N_SAMP * D_TOW) / 4;  // 262144 -> x-blocks are bid 0..1023
  int bid = blockIdx.x;
  int tid = threadIdx.x;
  int t = bid * 256 + tid;
  if (bid < 1024) {
    __shared__ int sbad;
    if (tid == 0) sbad = 0;
    float4 v = ((const float4*)x)[t];
    bool bad = !(((v.x == 0.f) || (v.x == 1.f)) &&
                 ((v.y == 0.f) || (v.y == 1.f)) &&
                 ((v.z == 0.f) || (v.z == 1.f)) &&
                 ((v.w == 0.f) || (v.w == 1.f)));
    ushort4 o;
    o.x = f2bf(v.x); o.y = f2bf(v.y); o.z = f2bf(v.z); o.w = f2bf(v.w);
    ((ushort4*)xb)[t] = o;
    __syncthreads();
    if (__ballot(bad) != 0ull && (tid & 63) == 0) sbad = 1;
    __syncthreads();
    if (tid == 0) flagArr[bid] = sbad;
  } else {
    const float c = -1.442695040888963f;
    int j = t - NX4;
    float4 v = ((const float4*)w0)[j];
    ushort4 o;
    o.x = f2bf(c * v.x); o.y = f2bf(c * v.y);
    o.z = f2bf(c * v.z); o.w = f2bf(c * v.w);
    ((ushort4*)w0b)[j] = o;
  }
}

__device__ __forceinline__ void g2l16(const void* g, void* l) {
  __builtin_amdgcn_global_load_lds(
      (const __attribute__((address_space(1))) void*)g,
      (__attribute__((address_space(3))) void*)l, 16, 0, 0);
}

// One block = one tower k x one 128-row chunk of samples.
// W0_k staged in LDS (XOR-swizzled, conflict-free a-frag reads).
// X B-fragments are read DIRECTLY from global: X is 2 MB bf16, L2-resident,
// and dropping sX halves LDS -> 4 blocks/CU (was 2).
// Block mapping: per XCD, k is the FAST index so the 16 towers sharing an
// n0-chunk run concurrently -> out[n][k0..k0+15] write-merges in L2 and the
// 32 KB X chunk is shared.
__global__ __launch_bounds__(256, 4) void towers_kernel(
    const ushort* __restrict__ xb, const ushort* __restrict__ w0b,
    const float* __restrict__ b0, const float* __restrict__ w1,
    const float* __restrict__ b1, const int* __restrict__ flagArr,
    float* __restrict__ out) {
  __shared__ __align__(16) ushort sW[128 * 128];  // 32 KB
  __shared__ float sRed[128][2];
  __shared__ int sBadW[4];

  int bid = blockIdx.x;
  int xcd = bid & 7;
  int idx = bid >> 3;            // 0..1023 per XCD
  int k  = xcd * 16 + (idx & 15);
  int n0 = (idx >> 4) * 128;

  int tid = threadIdx.x;
  int lane = tid & 63;
  int wave = tid >> 6;
  int q = lane >> 4;      // quad index (bits 4-5)
  int cl = lane & 15;

  const ushort* wg = w0b + k * (128 * 128);  // W0_k: [h][d] row-major bf16

  // Stage W tile. LDS dest = uniform base + lane*16 (HW rule); XOR swizzle
  // applied to the *global source* chunk: LDS[row][c] = global chunk c^(row&15).
#pragma unroll
  for (int i = 0; i < 8; ++i) {
    int base = wave * 8192 + i * 1024;       // byte offset, wave-uniform
    int row = wave * 32 + i * 4 + q;
    int c = cl ^ (row & 15);
    g2l16(wg + row * 128 + c * 8, (char*)sW + base);
  }

  // Binary-flag OR-reduce (1024 ints), overlapped with staging latency.
  int4 fv = ((const int4*)flagArr)[tid];     // 256 threads x 16B = 4 KB
  int anyb = fv.x | fv.y | fv.z | fv.w;
  unsigned long long mb = __ballot(anyb != 0);
  if (lane == 0) sBadW[wave] = (mb != 0ull) ? 1 : 0;

  __syncthreads();

  int R  = (wave >> 1) * 64;   // n-quadrant
  int Ch = (wave & 1) * 64;    // h-quadrant

  f32x4 acc[4][4];             // [hf][nf]
#pragma unroll
  for (int hf = 0; hf < 4; ++hf)
#pragma unroll
    for (int nf = 0; nf < 4; ++nf)
      acc[hf][nf] = (f32x4){0.f, 0.f, 0.f, 0.f};

  int aBase[4], bOff[4];
  const char* xgc = (const char*)(xb + n0 * 128);
#pragma unroll
  for (int f = 0; f < 4; ++f) {
    aBase[f] = (Ch + f * 16 + cl) * 256;             // LDS W row = h
    bOff[f]  = (R + f * 16 + cl) * 256 + q * 16;     // global X row = n
  }

#pragma unroll
  for (int t = 0; t < 4; ++t) {  // K = 128 = 4 * 32
    bf16x8 a[4], b[4];
#pragma unroll
    for (int nf = 0; nf < 4; ++nf)   // global loads first: issue early
      b[nf] = *(const bf16x8*)(xgc + bOff[nf] + t * 64);
    int ch = ((t * 4 + q) ^ cl) << 4;
#pragma unroll
    for (int hf = 0; hf < 4; ++hf)
      a[hf] = *(const bf16x8*)((const char*)sW + aBase[hf] + ch);
#pragma unroll
    for (int hf = 0; hf < 4; ++hf)
#pragma unroll
      for (int nf = 0; nf < 4; ++nf)
        acc[hf][nf] = __builtin_amdgcn_mfma_f32_16x16x32_bf16(
            a[hf], b[nf], acc[hf][nf], 0, 0, 0);
  }

  // Epilogue. acc already holds -log2e*(x.W0); bbs = -log2e*b0, so
  // sigmoid = rcp(1 + exp2(acc+bbs)). rcps paired: 2 trans -> 1.5 per elem.
  f32x4 bbs[4], wv[4];
#pragma unroll
  for (int hf = 0; hf < 4; ++hf) {
    int h = k * 128 + Ch + hf * 16 + q * 4;
    f32x4 b0v = *(const f32x4*)&b0[h];
    wv[hf] = *(const f32x4*)&w1[h];
    bbs[hf] = b0v * -1.442695040888963f;
  }
  float s[4] = {0.f, 0.f, 0.f, 0.f};
#pragma unroll
  for (int hf = 0; hf < 4; ++hf)
#pragma unroll
    for (int nf = 0; nf < 4; ++nf) {
      f32x4 qv = acc[hf][nf] + bbs[hf];
      float d0 = 1.0f + __builtin_amdgcn_exp2f(qv[0]);
      float d1 = 1.0f + __builtin_amdgcn_exp2f(qv[1]);
      float d2 = 1.0f + __builtin_amdgcn_exp2f(qv[2]);
      float d3 = 1.0f + __builtin_amdgcn_exp2f(qv[3]);
      float r01 = __builtin_amdgcn_rcpf(d0 * d1);
      float r23 = __builtin_amdgcn_rcpf(d2 * d3);
      s[nf] += wv[hf][0] * (r01 * d1);
      s[nf] += wv[hf][1] * (r01 * d0);
      s[nf] += wv[hf][2] * (r23 * d3);
      s[nf] += wv[hf][3] * (r23 * d2);
    }

#pragma unroll
  for (int m = 16; m <= 32; m <<= 1)
#pragma unroll
    for (int nf = 0; nf < 4; ++nf)
      s[nf] += __shfl_xor(s[nf], m, 64);

  if (q == 0) {
#pragma unroll
    for (int nf = 0; nf < 4; ++nf)
      sRed[R + nf * 16 + cl][wave & 1] = s[nf];
  }
  __syncthreads();

  if (tid < 128) {
    int anyBad = sBadW[0] | sBadW[1] | sBadW[2] | sBadW[3];
    float v = sRed[tid][0] + sRed[tid][1] + b1[k];
    if (anyBad == 0) v = fast_sigmoid(v);  // binary-input path
    out[(size_t)(n0 + tid) * D_TOW + k] = v;
  }
}

extern "C" void kernel_launch(void* const* d_in, const int* in_sizes, int n_in,
                              void* d_out, int out_size, void* d_ws, size_t ws_size,
                              hipStream_t stream) {
  const float* x  = (const float*)d_in[0];
  const float* w0 = (const float*)d_in[1];
  const float* b0 = (const float*)d_in[2];
  const float* w1 = (const float*)d_in[3];
  const float* b1 = (const float*)d_in[4];
  float* out = (float*)d_out;

  char* ws = (char*)d_ws;
  int* flagArr = (int*)ws;                                   // 4 KB
  ushort* xb  = (ushort*)(ws + 4096);                        // 2 MB
  ushort* w0b = (ushort*)(ws + 4096 + N_SAMP * D_TOW * 2);   // 4 MB

  int total4 = (N_SAMP * D_TOW + D_TOW * D_HID * D_TOW) / 4; // 786432
  prep_kernel<<<total4 / 256, 256, 0, stream>>>(x, w0, xb, w0b, flagArr);

  towers_kernel<<<8192, 256, 0, stream>>>(xb, w0b, b0, w1, b1, flagArr, out);
}

// Round 2
// 129.087 us; speedup vs baseline: 1.2166x; 1.2166x over previous
//
#include <hip/hip_runtime.h>
#include <hip/hip_bf16.h>
#include <stdint.h>

#define N_SAMP 8192
#define D_TOW  128
#define D_HID  128

typedef __bf16 bf16x8 __attribute__((ext_vector_type(8)));
typedef float  f32x4  __attribute__((ext_vector_type(4)));

__device__ __forceinline__ ushort f2bf(float f) {
  union { float f; uint32_t u; } c; c.f = f;
  uint32_t u = c.u;
  return (ushort)((u + 0x7FFFu + ((u >> 16) & 1u)) >> 16);  // RNE
}

// sigmoid via raw HW ops: v_exp_f32 + v_rcp_f32.
__device__ __forceinline__ float fast_sigmoid(float p) {
  float e = __builtin_amdgcn_exp2f(p * -1.442695040888963f);
  return __builtin_amdgcn_rcpf(1.0f + e);
}

// fp32 -> bf16 convert. W0 is pre-scaled by -log2(e) so the towers MFMA
// directly produces exp2 arguments. x path writes a per-block "saw
// non-binary" flag UNCONDITIONALLY (removes the hipMemsetAsync node).
__global__ __launch_bounds__(256) void prep_kernel(
    const float* __restrict__ x, const float* __restrict__ w0,
    ushort* __restrict__ xb, ushort* __restrict__ w0b,
    int* __restrict__ flagArr) {
  const int NX4 = (N_SAMP * D_TOW) / 4;  // 262144 -> x-blocks are bid 0..1023
  int bid = blockIdx.x;
  int tid = threadIdx.x;
  int t = bid * 256 + tid;
  if (bid < 1024) {
    __shared__ int sbad;
    if (tid == 0) sbad = 0;
    float4 v = ((const float4*)x)[t];
    bool bad = !(((v.x == 0.f) || (v.x == 1.f)) &&
                 ((v.y == 0.f) || (v.y == 1.f)) &&
                 ((v.z == 0.f) || (v.z == 1.f)) &&
                 ((v.w == 0.f) || (v.w == 1.f)));
    ushort4 o;
    o.x = f2bf(v.x); o.y = f2bf(v.y); o.z = f2bf(v.z); o.w = f2bf(v.w);
    ((ushort4*)xb)[t] = o;
    __syncthreads();
    if (__ballot(bad) != 0ull && (tid & 63) == 0) sbad = 1;
    __syncthreads();
    if (tid == 0) flagArr[bid] = sbad;
  } else {
    const float c = -1.442695040888963f;
    int j = t - NX4;
    float4 v = ((const float4*)w0)[j];
    ushort4 o;
    o.x = f2bf(c * v.x); o.y = f2bf(c * v.y);
    o.z = f2bf(c * v.z); o.w = f2bf(c * v.w);
    ((ushort4*)w0b)[j] = o;
  }
}

__device__ __forceinline__ void g2l16(const void* g, void* l) {
  __builtin_amdgcn_global_load_lds(
      (const __attribute__((address_space(1))) void*)g,
      (__attribute__((address_space(3))) void*)l, 16, 0, 0);
}

// One block = one tower k x one 128-row chunk of samples.
// Both X and W0_k staged in LDS, but in TWO k-half phases of 16 KB each:
// total LDS 33 KB -> 4 blocks/CU (R0's 66.5 KB gave only 2; R1's global-X
// b-frags were L2-latency-bound on the MFMA critical path).
// LDS rows are 64 bf16 (128 B, 8x16B slots); slot holds global chunk
// slot^(row&7) so a-frag/b-frag ds_read_b128 is <=2-way conflicted (free).
// Block mapping: per XCD, k is the FAST index -> the 16 towers sharing an
// n0-chunk run concurrently -> out[n][k0..k0+15] write-merges in L2 and the
// X chunk is L2-shared.
__global__ __launch_bounds__(256, 4) void towers_kernel(
    const ushort* __restrict__ xb, const ushort* __restrict__ w0b,
    const float* __restrict__ b0, const float* __restrict__ w1,
    const float* __restrict__ b1, const int* __restrict__ flagArr,
    float* __restrict__ out) {
  __shared__ __align__(16) ushort sX[128 * 64];  // 16 KB
  __shared__ __align__(16) ushort sW[128 * 64];  // 16 KB
  __shared__ float sRed[128][2];
  __shared__ int sBadW[4];

  int bid = blockIdx.x;
  int xcd = bid & 7;
  int idx = bid >> 3;            // 0..1023 per XCD
  int k  = xcd * 16 + (idx & 15);
  int n0 = (idx >> 4) * 128;

  int tid = threadIdx.x;
  int lane = tid & 63;
  int wave = tid >> 6;
  int q = lane >> 4;      // quad index (bits 4-5)
  int cl = lane & 15;

  const ushort* xg = xb + n0 * 128;          // [128][128] row-major bf16
  const ushort* wg = w0b + k * (128 * 128);  // W0_k: [h][d] row-major bf16

  // Binary-flag OR-reduce (1024 ints), issued before staging.
  int4 fv = ((const int4*)flagArr)[tid];     // 256 threads x 16B = 4 KB
  int anyb = fv.x | fv.y | fv.z | fv.w;
  unsigned long long mb = __ballot(anyb != 0);
  if (lane == 0) sBadW[wave] = (mb != 0ull) ? 1 : 0;

  int R  = (wave >> 1) * 64;   // n-quadrant
  int Ch = (wave & 1) * 64;    // h-quadrant

  f32x4 acc[4][4];             // [hf][nf]
#pragma unroll
  for (int hf = 0; hf < 4; ++hf)
#pragma unroll
    for (int nf = 0; nf < 4; ++nf)
      acc[hf][nf] = (f32x4){0.f, 0.f, 0.f, 0.f};

  // Row base byte-offsets (LDS row = 128 B).
  int aBase[4], bBase[4];
#pragma unroll
  for (int f = 0; f < 4; ++f) {
    aBase[f] = (Ch + f * 16 + cl) * 128;     // W row = h
    bBase[f] = (R + f * 16 + cl) * 128;      // X row = n
  }

  int rowl = lane >> 3;   // 0..7 within a 1KB staging chunk
  int slot = lane & 7;

#pragma unroll
  for (int kb = 0; kb < 2; ++kb) {
    // Stage the k-half [kb*64 .. kb*64+63] of both tiles.
    // LDS dest = uniform base + lane*16 (HW rule); XOR swizzle applied to
    // the *global source* chunk. Source stays 128B-contiguous per 8 lanes.
#pragma unroll
    for (int i = 0; i < 4; ++i) {
      int row = wave * 32 + i * 8 + rowl;
      int c = slot ^ (row & 7);
      int goff = row * 128 + kb * 64 + c * 8;   // element offset
      int lbase = (wave * 32 + i * 8) * 128;    // byte offset, wave-uniform
      g2l16(xg + goff, (char*)sX + lbase);
      g2l16(wg + goff, (char*)sW + lbase);
    }
    __syncthreads();

#pragma unroll
    for (int t = 0; t < 2; ++t) {  // 2 x K=32 per phase
      int ch = ((t * 4 + q) ^ (cl & 7)) << 4;   // swizzled 16B slot offset
      bf16x8 a[4], b[4];
#pragma unroll
      for (int hf = 0; hf < 4; ++hf)
        a[hf] = *(const bf16x8*)((const char*)sW + aBase[hf] + ch);
#pragma unroll
      for (int nf = 0; nf < 4; ++nf)
        b[nf] = *(const bf16x8*)((const char*)sX + bBase[nf] + ch);
#pragma unroll
      for (int hf = 0; hf < 4; ++hf)
#pragma unroll
        for (int nf = 0; nf < 4; ++nf)
          acc[hf][nf] = __builtin_amdgcn_mfma_f32_16x16x32_bf16(
              a[hf], b[nf], acc[hf][nf], 0, 0, 0);
    }
    if (kb == 0) __syncthreads();   // protect restage of phase 1
  }

  // Epilogue. acc already holds -log2e*(x.W0); bbs = -log2e*b0, so
  // sigmoid = rcp(1 + exp2(acc+bbs)). rcps paired: 2 trans -> 1.5 per elem.
  // C layout: col = n = R + nf*16 + cl ; row = h = Ch + hf*16 + q*4 + r.
  f32x4 bbs[4], wv[4];
#pragma unroll
  for (int hf = 0; hf < 4; ++hf) {
    int h = k * 128 + Ch + hf * 16 + q * 4;
    f32x4 b0v = *(const f32x4*)&b0[h];
    wv[hf] = *(const f32x4*)&w1[h];
    bbs[hf] = b0v * -1.442695040888963f;
  }
  float s[4] = {0.f, 0.f, 0.f, 0.f};
#pragma unroll
  for (int hf = 0; hf < 4; ++hf)
#pragma unroll
    for (int nf = 0; nf < 4; ++nf) {
      f32x4 qv = acc[hf][nf] + bbs[hf];
      float d0 = 1.0f + __builtin_amdgcn_exp2f(qv[0]);
      float d1 = 1.0f + __builtin_amdgcn_exp2f(qv[1]);
      float d2 = 1.0f + __builtin_amdgcn_exp2f(qv[2]);
      float d3 = 1.0f + __builtin_amdgcn_exp2f(qv[3]);
      float r01 = __builtin_amdgcn_rcpf(d0 * d1);
      float r23 = __builtin_amdgcn_rcpf(d2 * d3);
      s[nf] += wv[hf][0] * (r01 * d1);
      s[nf] += wv[hf][1] * (r01 * d0);
      s[nf] += wv[hf][2] * (r23 * d3);
      s[nf] += wv[hf][3] * (r23 * d2);
    }

#pragma unroll
  for (int m = 16; m <= 32; m <<= 1)
#pragma unroll
    for (int nf = 0; nf < 4; ++nf)
      s[nf] += __shfl_xor(s[nf], m, 64);

  if (q == 0) {
#pragma unroll
    for (int nf = 0; nf < 4; ++nf)
      sRed[R + nf * 16 + cl][wave & 1] = s[nf];
  }
  __syncthreads();

  if (tid < 128) {
    int anyBad = sBadW[0] | sBadW[1] | sBadW[2] | sBadW[3];
    float v = sRed[tid][0] + sRed[tid][1] + b1[k];
    if (anyBad == 0) v = fast_sigmoid(v);  // binary-input path
    out[(size_t)(n0 + tid) * D_TOW + k] = v;
  }
}

extern "C" void kernel_launch(void* const* d_in, const int* in_sizes, int n_in,
                              void* d_out, int out_size, void* d_ws, size_t ws_size,
                              hipStream_t stream) {
  const float* x  = (const float*)d_in[0];
  const float* w0 = (const float*)d_in[1];
  const float* b0 = (const float*)d_in[2];
  const float* w1 = (const float*)d_in[3];
  const float* b1 = (const float*)d_in[4];
  float* out = (float*)d_out;

  char* ws = (char*)d_ws;
  int* flagArr = (int*)ws;                                   // 4 KB
  ushort* xb  = (ushort*)(ws + 4096);                        // 2 MB
  ushort* w0b = (ushort*)(ws + 4096 + N_SAMP * D_TOW * 2);   // 4 MB

  int total4 = (N_SAMP * D_TOW + D_TOW * D_HID * D_TOW) / 4; // 786432
  prep_kernel<<<total4 / 256, 256, 0, stream>>>(x, w0, xb, w0b, flagArr);

  towers_kernel<<<8192, 256, 0, stream>>>(xb, w0b, b0, w1, b1, flagArr, out);
}

// Round 3
// 119.856 us; speedup vs baseline: 1.3103x; 1.0770x over previous
//
#include <hip/hip_runtime.h>
#include <hip/hip_bf16.h>
#include <stdint.h>

#define N_SAMP 8192
#define D_TOW  128
#define D_HID  128

typedef __bf16 bf16x8 __attribute__((ext_vector_type(8)));
typedef float  f32x4  __attribute__((ext_vector_type(4)));
typedef float  f32x2  __attribute__((ext_vector_type(2)));

__device__ __forceinline__ ushort f2bf(float f) {
  union { float f; uint32_t u; } c; c.f = f;
  uint32_t u = c.u;
  return (ushort)((u + 0x7FFFu + ((u >> 16) & 1u)) >> 16);  // RNE
}

// sigmoid via raw HW ops: v_exp_f32 + v_rcp_f32.
__device__ __forceinline__ float fast_sigmoid(float p) {
  float e = __builtin_amdgcn_exp2f(p * -1.442695040888963f);
  return __builtin_amdgcn_rcpf(1.0f + e);
}

// fp32 -> bf16 convert. W0 is pre-scaled by -log2(e) so the towers MFMA
// directly produces exp2 arguments. x path writes a per-block "saw
// non-binary" flag UNCONDITIONALLY (no memset needed). 1024-thread blocks
// -> flagArr is only 256 ints (towers reads 1 KB, not 4 KB).
__global__ __launch_bounds__(1024) void prep_kernel(
    const float* __restrict__ x, const float* __restrict__ w0,
    ushort* __restrict__ xb, ushort* __restrict__ w0b,
    int* __restrict__ flagArr) {
  const int NX4 = (N_SAMP * D_TOW) / 4;  // 262144 -> x-blocks are bid 0..255
  int bid = blockIdx.x;
  int tid = threadIdx.x;
  int t = bid * 1024 + tid;
  if (bid < 256) {
    __shared__ int sbad;
    if (tid == 0) sbad = 0;
    float4 v = ((const float4*)x)[t];
    bool bad = !(((v.x == 0.f) || (v.x == 1.f)) &&
                 ((v.y == 0.f) || (v.y == 1.f)) &&
                 ((v.z == 0.f) || (v.z == 1.f)) &&
                 ((v.w == 0.f) || (v.w == 1.f)));
    ushort4 o;
    o.x = f2bf(v.x); o.y = f2bf(v.y); o.z = f2bf(v.z); o.w = f2bf(v.w);
    ((ushort4*)xb)[t] = o;
    __syncthreads();
    if (__ballot(bad) != 0ull && (tid & 63) == 0) sbad = 1;
    __syncthreads();
    if (tid == 0) flagArr[bid] = sbad;
  } else {
    const float c = -1.442695040888963f;
    int j = t - NX4;
    float4 v = ((const float4*)w0)[j];
    ushort4 o;
    o.x = f2bf(c * v.x); o.y = f2bf(c * v.y);
    o.z = f2bf(c * v.z); o.w = f2bf(c * v.w);
    ((ushort4*)w0b)[j] = o;
  }
}

__device__ __forceinline__ void g2l16(const void* g, void* l) {
  __builtin_amdgcn_global_load_lds(
      (const __attribute__((address_space(1))) void*)g,
      (__attribute__((address_space(3))) void*)l, 16, 0, 0);
}

// One block = one tower k x one 128-row chunk of samples.
// Both X and W0_k staged in LDS in TWO k-half phases of 16 KB each:
// 33.5 KB LDS + 128-reg waves (64 VGPR + 64 acc AGPR) -> 4 blocks/CU.
// LDS rows are 64 bf16 (128 B, 8x16B slots); slot holds global chunk
// slot^(row&7) -> <=2-way ds_read_b128 conflicts (free, measured 0).
// b0 is folded into the accumulator init (no epilogue bias add); W0 was
// pre-scaled by -log2e so sigmoid = rcp(1 + exp2(acc)).
// Epilogue uses paired f32x2 math to hit v_pk_*_f32 (full-rate packed fp32).
__global__ __launch_bounds__(256, 4) void towers_kernel(
    const ushort* __restrict__ xb, const ushort* __restrict__ w0b,
    const float* __restrict__ b0, const float* __restrict__ w1,
    const float* __restrict__ b1, const int* __restrict__ flagArr,
    float* __restrict__ out) {
  __shared__ __align__(16) ushort sX[128 * 64];  // 16 KB
  __shared__ __align__(16) ushort sW[128 * 64];  // 16 KB
  __shared__ float sRed[128][2];
  __shared__ int sBadW[4];

  int bid = blockIdx.x;
  int xcd = bid & 7;
  int idx = bid >> 3;            // 0..1023 per XCD
  int k  = xcd * 16 + (idx & 15);
  int n0 = (idx >> 4) * 128;

  int tid = threadIdx.x;
  int lane = tid & 63;
  int wave = tid >> 6;
  int q = lane >> 4;      // quad index (bits 4-5)
  int cl = lane & 15;

  const ushort* xg = xb + n0 * 128;          // [128][128] row-major bf16
  const ushort* wg = w0b + k * (128 * 128);  // W0_k: [h][d] row-major bf16

  int R  = (wave >> 1) * 64;   // n-quadrant
  int Ch = (wave & 1) * 64;    // h-quadrant

  int rowl = lane >> 3;   // 0..7 within a 1KB staging chunk
  int slot = lane & 7;

  // Issue phase-0 staging first so the latency hides under flag read +
  // bias load + acc init.
#pragma unroll
  for (int i = 0; i < 4; ++i) {
    int row = wave * 32 + i * 8 + rowl;
    int c = slot ^ (row & 7);
    int goff = row * 128 + c * 8;
    int lbase = (wave * 32 + i * 8) * 128;
    g2l16(xg + goff, (char*)sX + lbase);
    g2l16(wg + goff, (char*)sW + lbase);
  }

  // Binary-flag OR-reduce (256 ints = 1 KB).
  int anyb = flagArr[tid];
  unsigned long long mb = __ballot(anyb != 0);
  if (lane == 0) sBadW[wave] = (mb != 0ull) ? 1 : 0;

  // acc init = -log2e * b0 (bias folded into MFMA accumulator).
  // C layout: col = n = R + nf*16 + cl ; row = h = Ch + hf*16 + q*4 + r.
  f32x4 acc[4][4];             // [hf][nf]
#pragma unroll
  for (int hf = 0; hf < 4; ++hf) {
    int h = k * 128 + Ch + hf * 16 + q * 4;
    f32x4 bbs = *(const f32x4*)&b0[h] * -1.442695040888963f;
#pragma unroll
    for (int nf = 0; nf < 4; ++nf)
      acc[hf][nf] = bbs;
  }

  // Row base byte-offsets (LDS row = 128 B).
  int aBase[4], bBase[4];
#pragma unroll
  for (int f = 0; f < 4; ++f) {
    aBase[f] = (Ch + f * 16 + cl) * 128;     // W row = h
    bBase[f] = (R + f * 16 + cl) * 128;      // X row = n
  }

#pragma unroll
  for (int kb = 0; kb < 2; ++kb) {
    __syncthreads();   // staged data visible

#pragma unroll
    for (int t = 0; t < 2; ++t) {  // 2 x K=32 per phase
      int ch = ((t * 4 + q) ^ (cl & 7)) << 4;   // swizzled 16B slot offset
      bf16x8 a[4], b[4];
#pragma unroll
      for (int hf = 0; hf < 4; ++hf)
        a[hf] = *(const bf16x8*)((const char*)sW + aBase[hf] + ch);
#pragma unroll
      for (int nf = 0; nf < 4; ++nf)
        b[nf] = *(const bf16x8*)((const char*)sX + bBase[nf] + ch);
      __builtin_amdgcn_s_setprio(1);
#pragma unroll
      for (int hf = 0; hf < 4; ++hf)
#pragma unroll
        for (int nf = 0; nf < 4; ++nf)
          acc[hf][nf] = __builtin_amdgcn_mfma_f32_16x16x32_bf16(
              a[hf], b[nf], acc[hf][nf], 0, 0, 0);
      __builtin_amdgcn_s_setprio(0);
    }

    if (kb == 0) {
      __syncthreads();   // everyone done reading phase-0 LDS
      // Stage the second k-half [64..127] of both tiles.
#pragma unroll
      for (int i = 0; i < 4; ++i) {
        int row = wave * 32 + i * 8 + rowl;
        int c = slot ^ (row & 7);
        int goff = row * 128 + 64 + c * 8;
        int lbase = (wave * 32 + i * 8) * 128;
        g2l16(xg + goff, (char*)sX + lbase);
        g2l16(wg + goff, (char*)sW + lbase);
      }
    }
  }

  // Epilogue: sigmoid = rcp(1 + exp2(acc)); rcps paired (2 trans -> 1.5
  // per elem); mul/fma paths paired as f32x2 for v_pk_*_f32.
  f32x2 s2[4] = {{0.f, 0.f}, {0.f, 0.f}, {0.f, 0.f}, {0.f, 0.f}};
#pragma unroll
  for (int hf = 0; hf < 4; ++hf) {
    int h = k * 128 + Ch + hf * 16 + q * 4;
    f32x4 wv = *(const f32x4*)&w1[h];
    f32x2 wa = {wv[0], wv[1]};
    f32x2 wb = {wv[2], wv[3]};
#pragma unroll
    for (int nf = 0; nf < 4; ++nf) {
      f32x4 qv = acc[hf][nf];
      f32x2 dA = {1.0f + __builtin_amdgcn_exp2f(qv[0]),
                  1.0f + __builtin_amdgcn_exp2f(qv[1])};
      f32x2 dB = {1.0f + __builtin_amdgcn_exp2f(qv[2]),
                  1.0f + __builtin_amdgcn_exp2f(qv[3])};
      float rA = __builtin_amdgcn_rcpf(dA[0] * dA[1]);
      float rB = __builtin_amdgcn_rcpf(dB[0] * dB[1]);
      f32x2 cA = (f32x2){dA[1], dA[0]} * (f32x2){rA, rA};
      f32x2 cB = (f32x2){dB[1], dB[0]} * (f32x2){rB, rB};
      s2[nf] += wa * cA;
      s2[nf] += wb * cB;
    }
  }
  float s[4];
#pragma unroll
  for (int nf = 0; nf < 4; ++nf)
    s[nf] = s2[nf][0] + s2[nf][1];

#pragma unroll
  for (int m = 16; m <= 32; m <<= 1)
#pragma unroll
    for (int nf = 0; nf < 4; ++nf)
      s[nf] += __shfl_xor(s[nf], m, 64);

  if (q == 0) {
#pragma unroll
    for (int nf = 0; nf < 4; ++nf)
      sRed[R + nf * 16 + cl][wave & 1] = s[nf];
  }
  __syncthreads();

  if (tid < 128) {
    int anyBad = sBadW[0] | sBadW[1] | sBadW[2] | sBadW[3];
    float v = sRed[tid][0] + sRed[tid][1] + b1[k];
    if (anyBad == 0) v = fast_sigmoid(v);  // binary-input path
    out[(size_t)(n0 + tid) * D_TOW + k] = v;
  }
}

extern "C" void kernel_launch(void* const* d_in, const int* in_sizes, int n_in,
                              void* d_out, int out_size, void* d_ws, size_t ws_size,
                              hipStream_t stream) {
  const float* x  = (const float*)d_in[0];
  const float* w0 = (const float*)d_in[1];
  const float* b0 = (const float*)d_in[2];
  const float* w1 = (const float*)d_in[3];
  const float* b1 = (const float*)d_in[4];
  float* out = (float*)d_out;

  char* ws = (char*)d_ws;
  int* flagArr = (int*)ws;                                   // 1 KB
  ushort* xb  = (ushort*)(ws + 4096);                        // 2 MB
  ushort* w0b = (ushort*)(ws + 4096 + N_SAMP * D_TOW * 2);   // 4 MB

  int total = (N_SAMP * D_TOW + D_TOW * D_HID * D_TOW) / 4;  // 786432 float4
  prep_kernel<<<total / 1024, 1024, 0, stream>>>(x, w0, xb, w0b, flagArr);

  towers_kernel<<<8192, 256, 0, stream>>>(xb, w0b, b0, w1, b1, flagArr, out);
}